// Round 5
// baseline (129.625 us; speedup 1.0000x reference)
//
#include <hip/hip_runtime.h>

// Problem: BATCH=8192, DIM=4096 units, SUB=2.
// ref: o = (x_slice @ W1[u]) @ W2[u]; p = f32 softmax(o); out = one_hot(argmax(p)).
//
// CORRECTNESS MODEL (verified via the round-4 diagnostic: absmax=0.5 =>
// every non-strip unit matched the np reference bitwise):
//  1. f32 einsum chain round-per-op (mul, mul, add; NO fma), h materialized
//     in f32 — numpy semantics. __f*_rn blocks -ffp-contract=fast.
//  2. softmax decision with t = fl(o1-o0):
//       t <= 0                -> argmax 0 (ties -> first index)
//       t >  0: e0 = np_expf(-t), e1 = 1.0; division by the shared sum
//               cannot merge exps differing >= 1 ulp, so argmax 1 <=> e0 < 1.
//     For |t| < 2^-22, every CPU-numpy expf path (glibc small-x early exit,
//     numpy SIMD poly ending in fma(r, ~1.0, 1.0)) yields fl(1 - t), with the
//     1.0 boundary at t = 2^-25 resolved by round-to-even (midpoint -> 1.0
//     -> tie -> argmax 0). So the strip decision is exactly:
//               argmax 1 <=> __fsub_rn(1.0f, t) < 1.0f
//     (ocml expf — round 2's failure — has a different hw-exp boundary; do
//     NOT use expf() here.)

#define BATCH 8192
#define DIMU  4096
#define NX    (BATCH * (size_t)DIMU * 2)          // 67108864
#define TOT_F4 ((size_t)BATCH * (size_t)(DIMU / 2))

__device__ __forceinline__ void unit_onehot(float x0, float x1,
                                            float4 w1, float4 w2,
                                            float& e0, float& e1) {
    // W layout (in,out): w.x=W[0][0], w.y=W[0][1], w.z=W[1][0], w.w=W[1][1]
    const float h0 = __fadd_rn(__fmul_rn(x0, w1.x), __fmul_rn(x1, w1.z));
    const float h1 = __fadd_rn(__fmul_rn(x0, w1.y), __fmul_rn(x1, w1.w));
    const float o0 = __fadd_rn(__fmul_rn(h0, w2.x), __fmul_rn(h1, w2.z));
    const float o1 = __fadd_rn(__fmul_rn(h0, w2.y), __fmul_rn(h1, w2.w));
    const float t  = __fsub_rn(o1, o0);
    // np-f32-softmax-faithful argmax (see header).
    const bool one = (t > 0.0f) && (__fsub_rn(1.0f, t) < 1.0f);
    e0 = one ? 0.0f : 1.0f;
    e1 = one ? 1.0f : 0.0f;
}

__global__ __launch_bounds__(256) void onehot_units_kernel(
    const float* __restrict__ x,
    const float* __restrict__ W1,
    const float* __restrict__ W2,
    float* __restrict__ out)
{
    const size_t stride = (size_t)gridDim.x * blockDim.x;
    const float4* __restrict__ x4   = reinterpret_cast<const float4*>(x);
    const float4* __restrict__ w1_4 = reinterpret_cast<const float4*>(W1); // W1[u] = 4 floats
    const float4* __restrict__ w2_4 = reinterpret_cast<const float4*>(W2);
    float4* __restrict__ out4 = reinterpret_cast<float4*>(out);

    for (size_t i = (size_t)blockIdx.x * blockDim.x + threadIdx.x;
         i < TOT_F4; i += stride) {
        // i covers batch b = i / 2048, unit pair p = i % 2048 -> units 2p, 2p+1
        const float4 xv = x4[i];
        const int u = ((int)(i & (size_t)(DIMU / 2 - 1))) * 2;
        const float4 w1a = w1_4[u];
        const float4 w1b = w1_4[u + 1];
        const float4 w2a = w2_4[u];
        const float4 w2b = w2_4[u + 1];

        float4 ov;
        unit_onehot(xv.x, xv.y, w1a, w2a, ov.x, ov.y);
        unit_onehot(xv.z, xv.w, w1b, w2b, ov.z, ov.w);
        out4[i] = ov;
    }
}

extern "C" void kernel_launch(void* const* d_in, const int* in_sizes, int n_in,
                              void* d_out, int out_size, void* d_ws, size_t ws_size,
                              hipStream_t stream) {
    // Default: setup_inputs() dict order {x, W1, W2}.
    const float* x  = (const float*)d_in[0];
    const float* W1 = (const float*)d_in[1];
    const float* W2 = (const float*)d_in[2];
    // Hardened input identification (validated by the round-4 diagnostic):
    // x is the uniquely-big input; W1 precedes W2 among the small inputs.
    if (n_in >= 3) {
        int xi = -1;
        for (int k = 0; k < 3; ++k) if (in_sizes[k] == (int)NX) xi = k;
        if (xi >= 0) {
            int wi = -1, wj = -1;
            for (int k = 0; k < 3; ++k) if (k != xi) { if (wi < 0) wi = k; else wj = k; }
            x  = (const float*)d_in[xi];
            W1 = (const float*)d_in[wi];
            W2 = (const float*)d_in[wj];
        }
    }
    float* out = (float*)d_out;

    // Memory-bound streaming: cap grid at 2048 blocks, grid-stride the rest.
    dim3 grid(2048), block(256);
    hipLaunchKernelGGL(onehot_units_kernel, grid, block, 0, stream,
                       x, W1, W2, out);
}

// Round 6
// 115.326 us; speedup vs baseline: 1.1240x; 1.1240x over previous
//
#include <hip/hip_runtime.h>

// Problem: BATCH=8192, DIM=4096 units, SUB=2.
// ref: o = (x_slice @ W1[u]) @ W2[u]; p = f32 softmax(o); out = one_hot(argmax(p)).
//
// CORRECTNESS MODEL (verified: round-5 PASS with absmax = 0.0):
//  1. f32 einsum chain round-per-op (mul, mul, add; NO fma), h materialized
//     in f32 — numpy semantics. __f*_rn blocks -ffp-contract=fast.
//  2. softmax decision with t = fl(o1-o0):
//       argmax 1  <=>  (t > 0) && (__fsub_rn(1.0f, t) < 1.0f)
//     (np expf on tiny args reduces to fl(1-t); boundary t=2^-25 round-to-even
//     -> tie -> argmax 0. Do NOT use device expf — different boundary.)
//
// PERF MODEL (round 5: 129.6 us = 4.1 TB/s, VMEM-issue bound — 6 VMEM ops per
// 16B of stream because weights were re-fetched every grid-stride iteration):
// each thread now OWNS one unit-pair p for ROWS=32 consecutive batch rows;
// weights live in 16 VGPRs loaded once; steady state is exactly 1 float4 load
// + 1 float4 store per 32B of HBM traffic. Wave lanes sit on consecutive p ->
// every x/out access is a contiguous 1KB segment. Target ~6.3 TB/s => ~85 us.

#define BATCH 8192
#define DIMU  4096
#define NPAIR (DIMU / 2)                       // 2048 unit-pairs (one float4 of x each)
#define NX    ((size_t)BATCH * DIMU * 2)       // 67108864
#define NTHREADS ((size_t)BATCH * NPAIR / 32)  // 524288 threads total
#define ROWS  32                               // batch rows per thread

__device__ __forceinline__ void unit_onehot(float x0, float x1,
                                            float4 w1, float4 w2,
                                            float& e0, float& e1) {
    // W layout (in,out): w.x=W[0][0], w.y=W[0][1], w.z=W[1][0], w.w=W[1][1]
    const float h0 = __fadd_rn(__fmul_rn(x0, w1.x), __fmul_rn(x1, w1.z));
    const float h1 = __fadd_rn(__fmul_rn(x0, w1.y), __fmul_rn(x1, w1.w));
    const float o0 = __fadd_rn(__fmul_rn(h0, w2.x), __fmul_rn(h1, w2.z));
    const float o1 = __fadd_rn(__fmul_rn(h0, w2.y), __fmul_rn(h1, w2.w));
    const float t  = __fsub_rn(o1, o0);
    const bool one = (t > 0.0f) && (__fsub_rn(1.0f, t) < 1.0f);
    e0 = one ? 0.0f : 1.0f;
    e1 = one ? 1.0f : 0.0f;
}

__global__ __launch_bounds__(256) void onehot_units_kernel(
    const float* __restrict__ x,
    const float* __restrict__ W1,
    const float* __restrict__ W2,
    float* __restrict__ out)
{
    const unsigned gid = blockIdx.x * blockDim.x + threadIdx.x;   // < 524288
    const unsigned p     = gid & (NPAIR - 1);      // unit-pair this thread owns
    const unsigned chunk = gid >> 11;              // which 32-row batch chunk
    const unsigned r0    = chunk * ROWS;

    const float4* __restrict__ x4   = reinterpret_cast<const float4*>(x);
    const float4* __restrict__ w1_4 = reinterpret_cast<const float4*>(W1);
    const float4* __restrict__ w2_4 = reinterpret_cast<const float4*>(W2);
    float4* __restrict__ out4 = reinterpret_cast<float4*>(out);

    // Weights for units 2p, 2p+1 — loaded ONCE, kept in VGPRs.
    const float4 w1a = w1_4[2 * p];
    const float4 w1b = w1_4[2 * p + 1];
    const float4 w2a = w2_4[2 * p];
    const float4 w2b = w2_4[2 * p + 1];

    size_t idx = (size_t)r0 * NPAIR + p;           // row-major in float4 units
    #pragma unroll 4
    for (int k = 0; k < ROWS; ++k, idx += NPAIR) {
        const float4 xv = x4[idx];
        float4 ov;
        unit_onehot(xv.x, xv.y, w1a, w2a, ov.x, ov.y);
        unit_onehot(xv.z, xv.w, w1b, w2b, ov.z, ov.w);
        out4[idx] = ov;
    }
}

extern "C" void kernel_launch(void* const* d_in, const int* in_sizes, int n_in,
                              void* d_out, int out_size, void* d_ws, size_t ws_size,
                              hipStream_t stream) {
    // Default: setup_inputs() dict order {x, W1, W2}.
    const float* x  = (const float*)d_in[0];
    const float* W1 = (const float*)d_in[1];
    const float* W2 = (const float*)d_in[2];
    // Hardened input identification (validated by the round-4 diagnostic):
    // x is the uniquely-big input; W1 precedes W2 among the small inputs.
    if (n_in >= 3) {
        int xi = -1;
        for (int k = 0; k < 3; ++k) if (in_sizes[k] == (int)NX) xi = k;
        if (xi >= 0) {
            int wi = -1, wj = -1;
            for (int k = 0; k < 3; ++k) if (k != xi) { if (wi < 0) wi = k; else wj = k; }
            x  = (const float*)d_in[xi];
            W1 = (const float*)d_in[wi];
            W2 = (const float*)d_in[wj];
        }
    }
    float* out = (float*)d_out;

    // 524288 threads: one unit-pair x 32 batch rows each. 2048 blocks x 256.
    dim3 grid((unsigned)(NTHREADS / 256)), block(256);
    hipLaunchKernelGGL(onehot_units_kernel, grid, block, 0, stream,
                       x, W1, W2, out);
}

// Round 8
// 104.875 us; speedup vs baseline: 1.2360x; 1.0997x over previous
//
#include <hip/hip_runtime.h>

// Problem: BATCH=8192, DIM=4096 units, SUB=2.
// ref: o = (x_slice @ W1[u]) @ W2[u]; p = f32 softmax(o); out = one_hot(argmax(p)).
//
// CORRECTNESS MODEL (verified: rounds 5-6 PASS, absmax = 0.0):
//  1. f32 einsum chain round-per-op (mul, mul, add; NO fma), h materialized
//     in f32 — numpy semantics. __f*_rn blocks -ffp-contract=fast.
//  2. softmax decision with t = fl(o1-o0):
//       argmax 1  <=>  (t > 0) && (__fsub_rn(1.0f, t) < 1.0f)
//     (np expf on tiny args reduces to fl(1-t); boundary t=2^-25 round-to-even
//     -> tie -> argmax 0. Do NOT use device expf — different boundary.)
//
// PERF LOG: r5 row-major + per-iter weight refetch: 129.6us (4.14 TB/s).
// r6 weights-in-VGPR, thread owns unit-pair x 32 rows: 115.3us (4.66 TB/s).
// r7: compile error (vector-element can't bind to float&) — fixed here.
// r8 (this): nontemporal x-loads/out-stores (touch-once streams, 256MB each,
// 8-16x L2 — nt skips L2 allocate/write-allocate churn) + explicit
// 4-load/4-compute/4-store bursts.

#define BATCH 8192
#define DIMU  4096
#define NPAIR (DIMU / 2)                       // 2048 unit-pairs (one float4 of x each)
#define NX    ((size_t)BATCH * DIMU * 2)       // 67108864
#define ROWS  32                               // batch rows per thread
#define NTHREADS ((size_t)BATCH * NPAIR / ROWS)  // 524288 threads total

typedef float f32x4 __attribute__((ext_vector_type(4)));

__device__ __forceinline__ float2 unit_onehot(float x0, float x1,
                                              f32x4 w1, f32x4 w2) {
    // W layout (in,out): w.x=W[0][0], w.y=W[0][1], w.z=W[1][0], w.w=W[1][1]
    const float h0 = __fadd_rn(__fmul_rn(x0, w1.x), __fmul_rn(x1, w1.z));
    const float h1 = __fadd_rn(__fmul_rn(x0, w1.y), __fmul_rn(x1, w1.w));
    const float o0 = __fadd_rn(__fmul_rn(h0, w2.x), __fmul_rn(h1, w2.z));
    const float o1 = __fadd_rn(__fmul_rn(h0, w2.y), __fmul_rn(h1, w2.w));
    const float t  = __fsub_rn(o1, o0);
    const bool one = (t > 0.0f) && (__fsub_rn(1.0f, t) < 1.0f);
    return make_float2(one ? 0.0f : 1.0f, one ? 1.0f : 0.0f);
}

__device__ __forceinline__ f32x4 pair_onehot(f32x4 xv, f32x4 w1a, f32x4 w2a,
                                             f32x4 w1b, f32x4 w2b) {
    const float2 ra = unit_onehot(xv.x, xv.y, w1a, w2a);
    const float2 rb = unit_onehot(xv.z, xv.w, w1b, w2b);
    f32x4 ov;
    ov.x = ra.x; ov.y = ra.y; ov.z = rb.x; ov.w = rb.y;
    return ov;
}

__global__ __launch_bounds__(256) void onehot_units_kernel(
    const float* __restrict__ x,
    const float* __restrict__ W1,
    const float* __restrict__ W2,
    float* __restrict__ out)
{
    const unsigned gid = blockIdx.x * blockDim.x + threadIdx.x;   // < 524288
    const unsigned p     = gid & (NPAIR - 1);      // unit-pair this thread owns
    const unsigned chunk = gid >> 11;              // which 32-row batch chunk

    const f32x4* __restrict__ x4   = reinterpret_cast<const f32x4*>(x);
    const f32x4* __restrict__ w1_4 = reinterpret_cast<const f32x4*>(W1);
    const f32x4* __restrict__ w2_4 = reinterpret_cast<const f32x4*>(W2);
    f32x4* __restrict__ out4 = reinterpret_cast<f32x4*>(out);

    // Weights for units 2p, 2p+1 — loaded ONCE via cache (reused data).
    const f32x4 w1a = w1_4[2 * p];
    const f32x4 w1b = w1_4[2 * p + 1];
    const f32x4 w2a = w2_4[2 * p];
    const f32x4 w2b = w2_4[2 * p + 1];

    size_t idx = (size_t)chunk * ROWS * NPAIR + p;   // row-major, float4 units
    #pragma unroll
    for (int g = 0; g < ROWS / 4; ++g, idx += 4 * (size_t)NPAIR) {
        // burst of 4 nontemporal loads (touch-once stream: skip L2 allocate)
        const f32x4 a = __builtin_nontemporal_load(&x4[idx]);
        const f32x4 b = __builtin_nontemporal_load(&x4[idx + NPAIR]);
        const f32x4 c = __builtin_nontemporal_load(&x4[idx + 2 * NPAIR]);
        const f32x4 d = __builtin_nontemporal_load(&x4[idx + 3 * NPAIR]);
        const f32x4 oa = pair_onehot(a, w1a, w2a, w1b, w2b);
        const f32x4 ob = pair_onehot(b, w1a, w2a, w1b, w2b);
        const f32x4 oc = pair_onehot(c, w1a, w2a, w1b, w2b);
        const f32x4 od = pair_onehot(d, w1a, w2a, w1b, w2b);
        // burst of 4 nontemporal stores (write-once stream: no L2 pollution)
        __builtin_nontemporal_store(oa, &out4[idx]);
        __builtin_nontemporal_store(ob, &out4[idx + NPAIR]);
        __builtin_nontemporal_store(oc, &out4[idx + 2 * NPAIR]);
        __builtin_nontemporal_store(od, &out4[idx + 3 * NPAIR]);
    }
}

extern "C" void kernel_launch(void* const* d_in, const int* in_sizes, int n_in,
                              void* d_out, int out_size, void* d_ws, size_t ws_size,
                              hipStream_t stream) {
    // Default: setup_inputs() dict order {x, W1, W2}.
    const float* x  = (const float*)d_in[0];
    const float* W1 = (const float*)d_in[1];
    const float* W2 = (const float*)d_in[2];
    // Hardened input identification (validated by the round-4 diagnostic):
    // x is the uniquely-big input; W1 precedes W2 among the small inputs.
    if (n_in >= 3) {
        int xi = -1;
        for (int k = 0; k < 3; ++k) if (in_sizes[k] == (int)NX) xi = k;
        if (xi >= 0) {
            int wi = -1, wj = -1;
            for (int k = 0; k < 3; ++k) if (k != xi) { if (wi < 0) wi = k; else wj = k; }
            x  = (const float*)d_in[xi];
            W1 = (const float*)d_in[wi];
            W2 = (const float*)d_in[wj];
        }
    }
    float* out = (float*)d_out;

    // 524288 threads: one unit-pair x 32 batch rows each. 2048 blocks x 256.
    dim3 grid((unsigned)(NTHREADS / 256)), block(256);
    hipLaunchKernelGGL(onehot_units_kernel, grid, block, 0, stream,
                       x, W1, W2, out);
}